// Round 2
// baseline (517.319 us; speedup 1.0000x reference)
//
#include <hip/hip_runtime.h>
#include <cmath>

// EstimatorQNNGen275: conv+sigmoid+mean -> 1-dim attention -> 4-layer tanh MLP
// (3x 512x4096x4096 GEMMs) -> pairwise-fidelity graph.
//
// R2: LDS-free direct-load GEMM. R1 post-mortem showed the staged GEMM was
// LDS-byte-throughput-bound (12 MB/CU through LDS ~= 45us of the 65us wall;
// SQ_LDS_BANK_CONFLICT saturated at 2^22). A is pre-converted to fp16 by the
// producing kernels' epilogues (identical RNE cast -> identical numerics);
// W is loaded fp32 and converted in-register. Register ping-pong (static
// indices), zero barriers, split-K=4.
//
// ws layout (bytes):
//   [0,2048)     c_buf (512 f32)
//   [2048,4096)  attn  (512 f32)
//   [4096,4736)  D     (10 dot accumulators, line-padded stride 16 f32)
//   [8192, +)    act1,act2,act3 (f32, 8MB each) ; a1h,a2h,a3h (fp16, 4MB each)
//                ; part (Z x 8MB split-K partials)

#define NEL (512 * 4096)

typedef float  floatx4 __attribute__((ext_vector_type(4)));
typedef _Float16 halfx8 __attribute__((ext_vector_type(8)));
typedef _Float16 halfx4 __attribute__((ext_vector_type(4)));

// ---------------- conv + sigmoid + mean (float4) ----------------
__global__ __launch_bounds__(256) void conv_mean_kernel(
    const float* __restrict__ x, const float* __restrict__ cw,
    const float* __restrict__ cb, float* __restrict__ c_out)
{
  __shared__ float sbuf[4];
  const int b = blockIdx.x;
  const float w00 = cw[0], w01 = cw[1], w10 = cw[2], w11 = cw[3];
  const float bias = cb[0];
  const float* xb = x + (size_t)b * 128 * 128;
  float acc = 0.f;
  for (int t = threadIdx.x; t < 127 * 32; t += 256) {
    const int i  = t >> 5;
    const int j0 = (t & 31) << 2;
    const float* pr0 = xb + i * 128 + j0;
    const float* pr1 = pr0 + 128;
    const float4 a4 = *reinterpret_cast<const float4*>(pr0);
    const float  a5 = pr0[4];
    const float4 b4 = *reinterpret_cast<const float4*>(pr1);
    const float  b5 = pr1[4];
    const float a[5] = {a4.x, a4.y, a4.z, a4.w, a5};
    const float bb[5] = {b4.x, b4.y, b4.z, b4.w, b5};
    #pragma unroll
    for (int m = 0; m < 4; ++m) {
      if (j0 + m < 127) {
        float v = w00 * a[m] + w01 * a[m + 1] + w10 * bb[m] + w11 * bb[m + 1] + bias;
        acc += 1.0f / (1.0f + __expf(-v));
      }
    }
  }
  #pragma unroll
  for (int off = 32; off > 0; off >>= 1) acc += __shfl_down(acc, off, 64);
  const int lane = threadIdx.x & 63, wv = threadIdx.x >> 6;
  if (lane == 0) sbuf[wv] = acc;
  __syncthreads();
  if (threadIdx.x == 0)
    c_out[b] = (sbuf[0] + sbuf[1] + sbuf[2] + sbuf[3]) * (1.0f / 16129.0f);
}

// ---------------- 1-dim attention ----------------
__global__ __launch_bounds__(64) void attn_kernel(
    const float* __restrict__ c, const float* __restrict__ rot,
    const float* __restrict__ ent, float* __restrict__ attn)
{
  const int i = blockIdx.x;
  const int lane = threadIdx.x;
  const float t = rot[0] * ent[0] * c[i];
  float vals[8], cj[8];
  float mx = -1e30f;
  #pragma unroll
  for (int u = 0; u < 8; ++u) {
    float cv = c[lane + u * 64];
    cj[u] = cv;
    vals[u] = t * cv;
    mx = fmaxf(mx, vals[u]);
  }
  #pragma unroll
  for (int off = 32; off > 0; off >>= 1) mx = fmaxf(mx, __shfl_down(mx, off, 64));
  mx = __shfl(mx, 0, 64);
  float se = 0.f, sw = 0.f;
  #pragma unroll
  for (int u = 0; u < 8; ++u) {
    float e = __expf(vals[u] - mx);
    se += e;
    sw += e * cj[u];
  }
  #pragma unroll
  for (int off = 32; off > 0; off >>= 1) {
    se += __shfl_down(se, off, 64);
    sw += __shfl_down(sw, off, 64);
  }
  if (lane == 0) attn[i] = sw / se;
}

// ---------------- layer 1 (outer product + tanh, f32 + fp16 copy) -----------
__global__ __launch_bounds__(256) void layer1_kernel(
    const float* __restrict__ attn, const float* __restrict__ W1,
    const float* __restrict__ b1, float* __restrict__ act1,
    _Float16* __restrict__ a1h)
{
  const int o = blockIdx.x * 256 + threadIdx.x;
  const int i = blockIdx.y;
  const float v = tanhf(attn[i] * W1[o] + b1[o]);
  act1[(size_t)i * 4096 + o] = v;
  a1h[(size_t)i * 4096 + o] = (_Float16)v;
}

// ---------------- LDS-free direct-load fp16 MFMA GEMM ----------------
// A16: 512 x 4096 fp16 row-major. W: 4096 x 4096 fp32 row-major (N x K).
// Grid (N/128, M/128, Z). Block 256 thr = 4 waves (2x2); wave tile 64x64 =
// 4x4 mfma 16x16x32. Frags loaded straight from global into MFMA layout:
//   lane (q=lane>>4, ml=lane&15): A row wm+i*16+ml, cols k0+q*8 (halfx8);
//   W row wn+j*16+ml, cols k0+q*8 (2x float4 -> cvt to halfx8, same RNE
//   cast as the old LDS-staged version -> identical numerics).
// Register ping-pong (af0/wf0 vs af1/wf1, all static indices), no LDS,
// no barriers. Cross-wave duplicate frags hit L1/L2 (24KB working set/iter).
template<bool FUSE>
__global__ __launch_bounds__(256, 2) void gemm_direct_kernel(
    const _Float16* __restrict__ A16, const float* __restrict__ W,
    const float* __restrict__ bias, float* __restrict__ C,
    _Float16* __restrict__ Ch)
{
  constexpr int K = 4096, N = 4096;
  const int tid  = threadIdx.x;
  const int lane = tid & 63;
  const int wave = tid >> 6;
  const int wm = (wave >> 1) * 64;
  const int wn = (wave & 1) * 64;
  const int q  = lane >> 4;
  const int ml = lane & 15;
  const int tileM = blockIdx.y * 128;
  const int tileN = blockIdx.x * 128;
  const int Kslice = K / gridDim.z;
  const int kbeg = blockIdx.z * Kslice;
  const int kend = kbeg + Kslice;
  float* Cb = FUSE ? C : C + (size_t)blockIdx.z * NEL;

  const _Float16* Abase = A16 + (size_t)(tileM + wm + ml) * K + q * 8;
  const float*    Wbase = W   + (size_t)(tileN + wn + ml) * K + q * 8;

  floatx4 acc[4][4] = {};
  halfx8 af0[4], af1[4];
  float4 wf0[4][2], wf1[4][2];

  auto loadA = [&](halfx8 (&af)[4], int k0) {
    #pragma unroll
    for (int i = 0; i < 4; ++i)
      af[i] = *reinterpret_cast<const halfx8*>(Abase + (size_t)i * 16 * K + k0);
  };
  auto loadW = [&](float4 (&wf)[4][2], int k0) {
    #pragma unroll
    for (int j = 0; j < 4; ++j) {
      const float* p = Wbase + (size_t)j * 16 * K + k0;
      wf[j][0] = *reinterpret_cast<const float4*>(p);
      wf[j][1] = *reinterpret_cast<const float4*>(p + 4);
    }
  };
  auto consume = [&](halfx8 (&af)[4], float4 (&wf)[4][2]) {
    halfx8 bf[4];
    #pragma unroll
    for (int j = 0; j < 4; ++j)
      bf[j] = halfx8{ (_Float16)wf[j][0].x, (_Float16)wf[j][0].y,
                      (_Float16)wf[j][0].z, (_Float16)wf[j][0].w,
                      (_Float16)wf[j][1].x, (_Float16)wf[j][1].y,
                      (_Float16)wf[j][1].z, (_Float16)wf[j][1].w };
    #pragma unroll
    for (int i = 0; i < 4; ++i)
      #pragma unroll
      for (int j = 0; j < 4; ++j)
        acc[i][j] = __builtin_amdgcn_mfma_f32_16x16x32_f16(af[i], bf[j], acc[i][j], 0, 0, 0);
  };

  // software pipeline, 2x unrolled ping-pong (static buffer indices)
  loadA(af0, kbeg);
  loadW(wf0, kbeg);
  for (int k0 = kbeg; k0 < kend; k0 += 64) {
    const bool m1 = (k0 + 32) < kend;
    const bool m2 = (k0 + 64) < kend;
    if (m1) { loadA(af1, k0 + 32); loadW(wf1, k0 + 32); }
    consume(af0, wf0);
    if (m2) { loadA(af0, k0 + 64); loadW(wf0, k0 + 64); }
    if (m1) consume(af1, wf1);
  }

  // C/D layout: col=lane&15, row=(lane>>4)*4+reg
  #pragma unroll
  for (int i = 0; i < 4; ++i) {
    const int row0 = tileM + wm + i * 16 + q * 4;
    #pragma unroll
    for (int j = 0; j < 4; ++j) {
      const int col = tileN + wn + j * 16 + ml;
      if (FUSE) {
        const float bv = bias[col];
        #pragma unroll
        for (int r = 0; r < 4; ++r) {
          const float v = tanhf(acc[i][j][r] + bv);
          Cb[(size_t)(row0 + r) * N + col] = v;
          if (Ch) Ch[(size_t)(row0 + r) * N + col] = (_Float16)v;
        }
      } else {
        #pragma unroll
        for (int r = 0; r < 4; ++r)
          Cb[(size_t)(row0 + r) * N + col] = acc[i][j][r];
      }
    }
  }
}

// ---------------- split-K combine: sum S slices + bias + tanh (+fp16) -------
template<int S, bool H>
__global__ __launch_bounds__(256) void combine_tanh_kernel(
    const float* __restrict__ part, const float* __restrict__ bias,
    float* __restrict__ outp, _Float16* __restrict__ houtp)
{
  const int i4 = blockIdx.x * 256 + threadIdx.x;  // < NEL/4
  const floatx4* p4 = (const floatx4*)part;
  floatx4 s = p4[i4];
  #pragma unroll
  for (int z = 1; z < S; ++z) s += p4[(size_t)z * (NEL / 4) + i4];
  const floatx4 bv = ((const floatx4*)bias)[i4 & 1023];
  floatx4 o;
  #pragma unroll
  for (int r = 0; r < 4; ++r) o[r] = tanhf(s[r] + bv[r]);
  ((floatx4*)outp)[i4] = o;
  if (H) {
    halfx4 h = { (_Float16)o[0], (_Float16)o[1], (_Float16)o[2], (_Float16)o[3] };
    ((halfx4*)houtp)[i4] = h;
  }
}

// ---------------- fid pairwise dots (low-contention) ----------------
__global__ __launch_bounds__(256) void fid_dots_kernel(
    const float* __restrict__ a1, const float* __restrict__ a2,
    const float* __restrict__ a3, const float* __restrict__ a4,
    float* __restrict__ D)
{
  __shared__ float sred[4][10];
  float s[10] = {0, 0, 0, 0, 0, 0, 0, 0, 0, 0};
  const int n4 = NEL / 4;
  const int stride = gridDim.x * blockDim.x;
  const floatx4* p1 = (const floatx4*)a1;
  const floatx4* p2 = (const floatx4*)a2;
  const floatx4* p3 = (const floatx4*)a3;
  const floatx4* p4 = (const floatx4*)a4;
  for (int i = blockIdx.x * 256 + threadIdx.x; i < n4; i += stride) {
    floatx4 v1 = p1[i], v2 = p2[i], v3 = p3[i], v4 = p4[i];
    #pragma unroll
    for (int r = 0; r < 4; ++r) {
      s[0] += v1[r] * v1[r]; s[1] += v1[r] * v2[r]; s[2] += v1[r] * v3[r];
      s[3] += v1[r] * v4[r]; s[4] += v2[r] * v2[r]; s[5] += v2[r] * v3[r];
      s[6] += v2[r] * v4[r]; s[7] += v3[r] * v3[r]; s[8] += v3[r] * v4[r];
      s[9] += v4[r] * v4[r];
    }
  }
  const int lane = threadIdx.x & 63, wv = threadIdx.x >> 6;
  #pragma unroll
  for (int p = 0; p < 10; ++p) {
    float v = s[p];
    #pragma unroll
    for (int off = 32; off > 0; off >>= 1) v += __shfl_down(v, off, 64);
    if (lane == 0) sred[wv][p] = v;
  }
  __syncthreads();
  if (threadIdx.x < 10) {
    float v = sred[0][threadIdx.x] + sred[1][threadIdx.x] +
              sred[2][threadIdx.x] + sred[3][threadIdx.x];
    atomicAdd(&D[threadIdx.x * 16], v);
  }
}

// ---------------- finalize graph weights ----------------
__global__ void finalize_kernel(const float* __restrict__ D, float* __restrict__ wout)
{
  const int i = threadIdx.x;
  if (i >= 16) return;
  const int p = i >> 2, qq = i & 3;
  const int a = p < qq ? p : qq;
  const int b = p < qq ? qq : p;
  const int base[4] = {0, 4, 7, 9};
  const float dpq = D[(base[a] + (b - a)) * 16];
  const float npv = sqrtf(D[base[p] * 16]) + 1e-12f;
  const float nqv = sqrtf(D[base[qq] * 16]) + 1e-12f;
  const float ch = dpq / (npv * nqv);
  const float fid = ch * ch;
  wout[i] = (fid >= 0.8f && p != qq) ? 1.0f : 0.0f;
}

extern "C" void kernel_launch(void* const* d_in, const int* in_sizes, int n_in,
                              void* d_out, int out_size, void* d_ws, size_t ws_size,
                              hipStream_t stream)
{
  const float* x   = (const float*)d_in[0];
  const float* cw  = (const float*)d_in[1];
  const float* cb  = (const float*)d_in[2];
  const float* rot = (const float*)d_in[3];
  const float* ent = (const float*)d_in[4];
  const float* W1  = (const float*)d_in[5];
  const float* b1  = (const float*)d_in[6];
  const float* W2  = (const float*)d_in[7];
  const float* b2  = (const float*)d_in[8];
  const float* W3  = (const float*)d_in[9];
  const float* b3  = (const float*)d_in[10];
  const float* W4  = (const float*)d_in[11];
  const float* b4  = (const float*)d_in[12];
  float* out = (float*)d_out;

  char*  ws    = (char*)d_ws;
  float* c_buf = (float*)(ws + 0);
  float* attn  = (float*)(ws + 2048);
  float* D     = (float*)(ws + 4096);
  float* act1  = (float*)(ws + 8192);
  float* act2  = act1 + NEL;
  float* act3  = act2 + NEL;
  _Float16* a1h = (_Float16*)(act3 + NEL);
  _Float16* a2h = a1h + NEL;
  _Float16* a3h = a2h + NEL;
  float* part  = (float*)(a3h + NEL);  // Z x NEL fp32 split-K partials
  float* wout  = out + NEL;

  const size_t base_need = 8192 + (size_t)3 * NEL * 4 + (size_t)3 * NEL * 2;
  const bool sk4 = ws_size >= base_need + (size_t)4 * NEL * 4;

  hipMemsetAsync(D, 0, 10 * 16 * sizeof(float), stream);
  conv_mean_kernel<<<512, 256, 0, stream>>>(x, cw, cb, c_buf);
  attn_kernel<<<512, 64, 0, stream>>>(c_buf, rot, ent, attn);
  layer1_kernel<<<dim3(16, 512), 256, 0, stream>>>(attn, W1, b1, act1, a1h);

  const int cgrid = NEL / 4 / 256;
  if (sk4) {
    dim3 g(32, 4, 4);  // 512 blocks, barrier-free waves, split-K=4
    gemm_direct_kernel<false><<<g, 256, 0, stream>>>(a1h, W2, nullptr, part, nullptr);
    combine_tanh_kernel<4, true><<<cgrid, 256, 0, stream>>>(part, b2, act2, a2h);
    gemm_direct_kernel<false><<<g, 256, 0, stream>>>(a2h, W3, nullptr, part, nullptr);
    combine_tanh_kernel<4, true><<<cgrid, 256, 0, stream>>>(part, b3, act3, a3h);
    gemm_direct_kernel<false><<<g, 256, 0, stream>>>(a3h, W4, nullptr, part, nullptr);
    combine_tanh_kernel<4, false><<<cgrid, 256, 0, stream>>>(part, b4, out, nullptr);
  } else {
    dim3 g(32, 4, 1);  // fused bias+tanh epilogue, full-K blocks
    gemm_direct_kernel<true><<<g, 256, 0, stream>>>(a1h, W2, b2, act2, a2h);
    gemm_direct_kernel<true><<<g, 256, 0, stream>>>(a2h, W3, b3, act3, a3h);
    gemm_direct_kernel<true><<<g, 256, 0, stream>>>(a3h, W4, b4, out, nullptr);
  }

  fid_dots_kernel<<<256, 256, 0, stream>>>(act1, act2, act3, out, D);
  finalize_kernel<<<1, 64, 0, stream>>>(D, wout);
}

// Round 4
// 423.527 us; speedup vs baseline: 1.2215x; 1.2215x over previous
//
#include <hip/hip_runtime.h>
#include <cmath>

// EstimatorQNNGen275: conv+sigmoid+mean -> 1-dim attention -> 4-layer tanh MLP
// (3x 512x4096x4096 GEMMs via fp16 MFMA, split-K=8, dbuf raw-barrier pipeline)
// -> pairwise-fidelity graph.
//
// R4: (a) GEMM LDS 40960->32768 B/block (LDK=32 + 16B-unit XOR swizzle,
//     unit' = unit ^ (row&3)). R1 showed Occupancy 29% (~3 blocks/CU: 4x40960
//     is EXACTLY the 160KiB pool) and a saturated bank-conflict counter;
//     32KB/block guarantees 4 blocks/CU and the swizzle kills the LDK=32
//     power-of-2 conflicts while keeping all halfx8 accesses 16B-aligned.
//     (b) attn fused into layer1 (wave 0 computes the identical shuffle-tree
//     softmax). (c) no XCD swizzle (R1: it raised FETCH 71->107MB).
//
// ws layout (bytes):
//   [0,2048)     c_buf (512 f32)
//   [4096,4736)  D     (10 dot accumulators, line-padded stride 16 f32)
//   [8192,...)   act1 ; act2 ; act3 ; part (8 x 8MB split-K partials)

#define NEL (512 * 4096)

typedef float  floatx4 __attribute__((ext_vector_type(4)));
typedef _Float16 halfx8 __attribute__((ext_vector_type(8)));

#define BM 128
#define BN 128
#define BK 32
#define LDK 32  // halfs per row (64 B); conflicts handled by XOR swizzle

// ---------------- conv + sigmoid + mean (float4) ----------------
__global__ __launch_bounds__(256) void conv_mean_kernel(
    const float* __restrict__ x, const float* __restrict__ cw,
    const float* __restrict__ cb, float* __restrict__ c_out)
{
  __shared__ float sbuf[4];
  const int b = blockIdx.x;
  const float w00 = cw[0], w01 = cw[1], w10 = cw[2], w11 = cw[3];
  const float bias = cb[0];
  const float* xb = x + (size_t)b * 128 * 128;
  float acc = 0.f;
  for (int t = threadIdx.x; t < 127 * 32; t += 256) {
    const int i  = t >> 5;
    const int j0 = (t & 31) << 2;
    const float* pr0 = xb + i * 128 + j0;
    const float* pr1 = pr0 + 128;
    const float4 a4 = *reinterpret_cast<const float4*>(pr0);
    const float  a5 = pr0[4];
    const float4 b4 = *reinterpret_cast<const float4*>(pr1);
    const float  b5 = pr1[4];
    const float a[5] = {a4.x, a4.y, a4.z, a4.w, a5};
    const float bb[5] = {b4.x, b4.y, b4.z, b4.w, b5};
    #pragma unroll
    for (int m = 0; m < 4; ++m) {
      if (j0 + m < 127) {
        float v = w00 * a[m] + w01 * a[m + 1] + w10 * bb[m] + w11 * bb[m + 1] + bias;
        acc += 1.0f / (1.0f + __expf(-v));
      }
    }
  }
  #pragma unroll
  for (int off = 32; off > 0; off >>= 1) acc += __shfl_down(acc, off, 64);
  const int lane = threadIdx.x & 63, wv = threadIdx.x >> 6;
  if (lane == 0) sbuf[wv] = acc;
  __syncthreads();
  if (threadIdx.x == 0)
    c_out[b] = (sbuf[0] + sbuf[1] + sbuf[2] + sbuf[3]) * (1.0f / 16129.0f);
}

// -------- attention (wave 0, exact replica) + layer 1 fused --------
__global__ __launch_bounds__(256) void attn_layer1_kernel(
    const float* __restrict__ c, const float* __restrict__ rot,
    const float* __restrict__ ent, const float* __restrict__ W1,
    const float* __restrict__ b1, float* __restrict__ act1)
{
  __shared__ float sattn;
  const int i = blockIdx.x;
  if (threadIdx.x < 64) {
    const int lane = threadIdx.x;
    const float t = rot[0] * ent[0] * c[i];
    float vals[8], cj[8];
    float mx = -1e30f;
    #pragma unroll
    for (int u = 0; u < 8; ++u) {
      float cv = c[lane + u * 64];
      cj[u] = cv;
      vals[u] = t * cv;
      mx = fmaxf(mx, vals[u]);
    }
    #pragma unroll
    for (int off = 32; off > 0; off >>= 1) mx = fmaxf(mx, __shfl_down(mx, off, 64));
    mx = __shfl(mx, 0, 64);
    float se = 0.f, sw = 0.f;
    #pragma unroll
    for (int u = 0; u < 8; ++u) {
      float e = __expf(vals[u] - mx);
      se += e;
      sw += e * cj[u];
    }
    #pragma unroll
    for (int off = 32; off > 0; off >>= 1) {
      se += __shfl_down(se, off, 64);
      sw += __shfl_down(sw, off, 64);
    }
    if (lane == 0) sattn = sw / se;
  }
  __syncthreads();
  const float av = sattn;
  #pragma unroll
  for (int k = 0; k < 16; ++k) {
    const int o = k * 256 + threadIdx.x;
    act1[(size_t)i * 4096 + o] = tanhf(av * W1[o] + b1[o]);
  }
}

// ---------------- fp16-MFMA GEMM (split-K, dbuf, raw barrier, XOR-swz) ------
// A: M x K fp32 row-major (M=512), W: N x K fp32 row-major (4096x4096).
// 128x128 tile, BK=32, 256 thr = 4 waves (2x2), wave = 64x64 = 4x4 mfma tiles.
// LDS layout: [2][128][32] halfs per operand (64 B rows). Physical 16B unit
// for logical unit u of row r is u ^ (r&3) -- bijective per row, 16B-aligned,
// spreads the 16-rows-x-4-units b128 access across all banks.
// Raw barrier + lgkm-only drain (R1): prefetch global loads stay in flight.
__global__ __launch_bounds__(256, 4) void gemm_kernel(
    const float* __restrict__ A, const float* __restrict__ W,
    float* __restrict__ part)
{
  __shared__ _Float16 As[2][BM][LDK];
  __shared__ _Float16 Ws[2][BN][LDK];
  const int K = 4096, N = 4096;
  const int tid  = threadIdx.x;
  const int lane = tid & 63;
  const int wave = tid >> 6;
  const int wm = (wave >> 1) * 64;
  const int wn = (wave & 1) * 64;
  const int q  = lane >> 4;
  const int ml = lane & 15;
  const int tileM = blockIdx.y * BM;
  const int tileN = blockIdx.x * BN;
  const int kbeg = blockIdx.z * 512;   // split-K=8: K/8 = 512
  const int kend = kbeg + 512;
  float* Cb = part + (size_t)blockIdx.z * NEL;

  floatx4 acc[4][4] = {};

  // staging map: thread handles rows r0, r0+64; logical 16B unit u0 = tid&3
  const int r0 = tid >> 2;
  const int u0 = tid & 3;
  const int su0 = (u0 ^ (r0 & 3)) << 3;   // swizzled col (halfs); (r0+64)&3 == r0&3
  // fragment read: logical unit q of row (..+ml) -> physical q ^ (ml&3)
  const int sq = (q ^ (ml & 3)) << 3;

  float4 pa[4], pw[4];
  auto load_tile = [&](int k0) {
    #pragma unroll
    for (int u = 0; u < 2; ++u) {
      const float* ap = A + (size_t)(tileM + r0 + u * 64) * K + k0 + u0 * 8;
      pa[2 * u]     = *reinterpret_cast<const float4*>(ap);
      pa[2 * u + 1] = *reinterpret_cast<const float4*>(ap + 4);
      const float* wp = W + (size_t)(tileN + r0 + u * 64) * K + k0 + u0 * 8;
      pw[2 * u]     = *reinterpret_cast<const float4*>(wp);
      pw[2 * u + 1] = *reinterpret_cast<const float4*>(wp + 4);
    }
  };
  auto store_tile = [&](int buf) {
    #pragma unroll
    for (int u = 0; u < 2; ++u) {
      halfx8 ha = { (_Float16)pa[2*u].x, (_Float16)pa[2*u].y,
                    (_Float16)pa[2*u].z, (_Float16)pa[2*u].w,
                    (_Float16)pa[2*u+1].x, (_Float16)pa[2*u+1].y,
                    (_Float16)pa[2*u+1].z, (_Float16)pa[2*u+1].w };
      *reinterpret_cast<halfx8*>(&As[buf][r0 + u * 64][su0]) = ha;
      halfx8 hw = { (_Float16)pw[2*u].x, (_Float16)pw[2*u].y,
                    (_Float16)pw[2*u].z, (_Float16)pw[2*u].w,
                    (_Float16)pw[2*u+1].x, (_Float16)pw[2*u+1].y,
                    (_Float16)pw[2*u+1].z, (_Float16)pw[2*u+1].w };
      *reinterpret_cast<halfx8*>(&Ws[buf][r0 + u * 64][su0]) = hw;
    }
  };

  // prologue: fill buf 0
  load_tile(kbeg);
  store_tile(0);
  int cur = 0;

  for (int k0 = kbeg; k0 < kend; k0 += BK) {
    const bool more = (k0 + BK < kend);
    if (more) load_tile(k0 + BK);   // stays in flight across the raw barrier

    // Publish prior ds_writes, then barrier WITHOUT draining vmcnt.
    asm volatile("s_waitcnt lgkmcnt(0)" ::: "memory");
    __builtin_amdgcn_s_barrier();

    halfx8 af[4], bf[4];
    #pragma unroll
    for (int i = 0; i < 4; ++i)
      af[i] = *reinterpret_cast<const halfx8*>(&As[cur][wm + i * 16 + ml][sq]);
    #pragma unroll
    for (int j = 0; j < 4; ++j)
      bf[j] = *reinterpret_cast<const halfx8*>(&Ws[cur][wn + j * 16 + ml][sq]);

    #pragma unroll
    for (int i = 0; i < 4; ++i)
      #pragma unroll
      for (int j = 0; j < 4; ++j)
        acc[i][j] = __builtin_amdgcn_mfma_f32_16x16x32_f16(af[i], bf[j], acc[i][j], 0, 0, 0);

    if (more) store_tile(cur ^ 1);  // compiler's vmcnt wait lands here
    cur ^= 1;
  }

  // C/D layout: col=lane&15, row=(lane>>4)*4+reg
  #pragma unroll
  for (int i = 0; i < 4; ++i) {
    const int row0 = tileM + wm + i * 16 + q * 4;
    #pragma unroll
    for (int j = 0; j < 4; ++j) {
      const int col = tileN + wn + j * 16 + ml;
      #pragma unroll
      for (int r = 0; r < 4; ++r)
        Cb[(size_t)(row0 + r) * N + col] = acc[i][j][r];
    }
  }
}

// ---------------- split-K combine: sum 8 slices + bias + tanh ----------------
__global__ __launch_bounds__(256) void combine_tanh_kernel(
    const float* __restrict__ part, const float* __restrict__ bias,
    float* __restrict__ outp)
{
  const int i4 = blockIdx.x * 256 + threadIdx.x;  // < NEL/4
  const floatx4* p4 = (const floatx4*)part;
  floatx4 s = p4[i4];
  #pragma unroll
  for (int z = 1; z < 8; ++z) s += p4[(size_t)z * (NEL / 4) + i4];
  const floatx4 bv = ((const floatx4*)bias)[i4 & 1023];
  floatx4 o;
  #pragma unroll
  for (int r = 0; r < 4; ++r) o[r] = tanhf(s[r] + bv[r]);
  ((floatx4*)outp)[i4] = o;
}

// ---------------- fid pairwise dots (low-contention) ----------------
__global__ __launch_bounds__(256) void fid_dots_kernel(
    const float* __restrict__ a1, const float* __restrict__ a2,
    const float* __restrict__ a3, const float* __restrict__ a4,
    float* __restrict__ D)
{
  __shared__ float sred[4][10];
  float s[10] = {0, 0, 0, 0, 0, 0, 0, 0, 0, 0};
  const int n4 = NEL / 4;
  const int stride = gridDim.x * blockDim.x;
  const floatx4* p1 = (const floatx4*)a1;
  const floatx4* p2 = (const floatx4*)a2;
  const floatx4* p3 = (const floatx4*)a3;
  const floatx4* p4 = (const floatx4*)a4;
  for (int i = blockIdx.x * 256 + threadIdx.x; i < n4; i += stride) {
    floatx4 v1 = p1[i], v2 = p2[i], v3 = p3[i], v4 = p4[i];
    #pragma unroll
    for (int r = 0; r < 4; ++r) {
      s[0] += v1[r] * v1[r]; s[1] += v1[r] * v2[r]; s[2] += v1[r] * v3[r];
      s[3] += v1[r] * v4[r]; s[4] += v2[r] * v2[r]; s[5] += v2[r] * v3[r];
      s[6] += v2[r] * v4[r]; s[7] += v3[r] * v3[r]; s[8] += v3[r] * v4[r];
      s[9] += v4[r] * v4[r];
    }
  }
  const int lane = threadIdx.x & 63, wv = threadIdx.x >> 6;
  #pragma unroll
  for (int p = 0; p < 10; ++p) {
    float v = s[p];
    #pragma unroll
    for (int off = 32; off > 0; off >>= 1) v += __shfl_down(v, off, 64);
    if (lane == 0) sred[wv][p] = v;
  }
  __syncthreads();
  if (threadIdx.x < 10) {
    float v = sred[0][threadIdx.x] + sred[1][threadIdx.x] +
              sred[2][threadIdx.x] + sred[3][threadIdx.x];
    atomicAdd(&D[threadIdx.x * 16], v);
  }
}

// ---------------- finalize graph weights ----------------
__global__ void finalize_kernel(const float* __restrict__ D, float* __restrict__ wout)
{
  const int i = threadIdx.x;
  if (i >= 16) return;
  const int p = i >> 2, qq = i & 3;
  const int a = p < qq ? p : qq;
  const int b = p < qq ? qq : p;
  const int base[4] = {0, 4, 7, 9};
  const float dpq = D[(base[a] + (b - a)) * 16];
  const float npv = sqrtf(D[base[p] * 16]) + 1e-12f;
  const float nqv = sqrtf(D[base[qq] * 16]) + 1e-12f;
  const float ch = dpq / (npv * nqv);
  const float fid = ch * ch;
  wout[i] = (fid >= 0.8f && p != qq) ? 1.0f : 0.0f;
}

extern "C" void kernel_launch(void* const* d_in, const int* in_sizes, int n_in,
                              void* d_out, int out_size, void* d_ws, size_t ws_size,
                              hipStream_t stream)
{
  const float* x   = (const float*)d_in[0];
  const float* cw  = (const float*)d_in[1];
  const float* cb  = (const float*)d_in[2];
  const float* rot = (const float*)d_in[3];
  const float* ent = (const float*)d_in[4];
  const float* W1  = (const float*)d_in[5];
  const float* b1  = (const float*)d_in[6];
  const float* W2  = (const float*)d_in[7];
  const float* b2  = (const float*)d_in[8];
  const float* W3  = (const float*)d_in[9];
  const float* b3  = (const float*)d_in[10];
  const float* W4  = (const float*)d_in[11];
  const float* b4  = (const float*)d_in[12];
  float* out = (float*)d_out;

  char*  ws    = (char*)d_ws;
  float* c_buf = (float*)(ws + 0);
  float* D     = (float*)(ws + 4096);
  float* act1  = (float*)(ws + 8192);
  float* act2  = act1 + NEL;
  float* act3  = act2 + NEL;
  float* part  = act3 + NEL;  // 8 x NEL fp32 split-K partials
  float* wout  = out + NEL;

  hipMemsetAsync(D, 0, 10 * 16 * sizeof(float), stream);
  conv_mean_kernel<<<512, 256, 0, stream>>>(x, cw, cb, c_buf);
  attn_layer1_kernel<<<512, 256, 0, stream>>>(c_buf, rot, ent, W1, b1, act1);

  const int cgrid = NEL / 4 / 256;
  dim3 g(32, 4, 8);  // 1024 blocks -> 4 blocks/CU (32KB LDS each)
  gemm_kernel<<<g, 256, 0, stream>>>(act1, W2, part);
  combine_tanh_kernel<<<cgrid, 256, 0, stream>>>(part, b2, act2);
  gemm_kernel<<<g, 256, 0, stream>>>(act2, W3, part);
  combine_tanh_kernel<<<cgrid, 256, 0, stream>>>(part, b3, act3);
  gemm_kernel<<<g, 256, 0, stream>>>(act3, W4, part);
  combine_tanh_kernel<<<cgrid, 256, 0, stream>>>(part, b4, out);

  fid_dots_kernel<<<256, 256, 0, stream>>>(act1, act2, act3, out, D);
  finalize_kernel<<<1, 64, 0, stream>>>(D, wout);
}